// Round 7
// baseline (382.109 us; speedup 1.0000x reference)
//
#include <hip/hip_runtime.h>
#include <hip/hip_bf16.h>

#define N_NODES 50000
#define N_PAD   50048
#define N_EDGES 800000
#define E_TOT   850000
#define NB      1024
#define ESM_DIM 480
#define HD      128
#define NBUCK   196          // buckets of 256 dst nodes
#define EPB     3321         // edges per block for 256 blocks
#define GAT1_BLKS 1563       // ceil(50000/32)

typedef short short8 __attribute__((ext_vector_type(8)));
typedef unsigned short ushort8 __attribute__((ext_vector_type(8)));
typedef float f32x4 __attribute__((ext_vector_type(4)));

__device__ __forceinline__ float bf2f(unsigned int u) {
    union { unsigned int i; float f; } c; c.i = u << 16; return c.f;
}
__device__ __forceinline__ unsigned short f2bf(float f) {
    union { float f; unsigned int i; } c; c.f = f;
    unsigned int i = c.i;
    return (unsigned short)((i + 0x7FFFu + ((i >> 16) & 1u)) >> 16);
}

// ================= mega1: hist1 | gat1 linear+alphas | LSTM split-K GEMM =================

__device__ void dev_hist1(const int* __restrict__ ei, int* __restrict__ cnt, int blk) {
    __shared__ int hist[NBUCK];
    int t = threadIdx.x;
    for (int u = t; u < NBUCK; u += 256) hist[u] = 0;
    __syncthreads();
    int e0 = blk * EPB;
    int e1 = (e0 + EPB < E_TOT) ? e0 + EPB : E_TOT;
    for (int e = e0 + t; e < e1; e += 256) {
        int d = (e < N_EDGES) ? ei[N_EDGES + e] : (e - N_EDGES);
        atomicAdd(&hist[d >> 8], 1);
    }
    __syncthreads();
    for (int u = t; u < NBUCK; u += 256) cnt[u * 256 + blk] = hist[u];
}

__device__ void dev_gat1(const float* __restrict__ X, const float* __restrict__ W,
                         const float* __restrict__ asrc, const float* __restrict__ adst,
                         unsigned short* __restrict__ out,
                         float* __restrict__ alpha_s, float* __restrict__ alpha_d, int blk) {
    __shared__ float Xs[32][23];
    __shared__ float Ws[128][21];
    __shared__ float w_as[21], w_ad[21];
    int t = threadIdx.x;
    int r0 = blk * 32;
    for (int idx = t; idx < 128 * 21; idx += 256) Ws[idx / 21][idx % 21] = W[idx];
    for (int idx = t; idx < 32 * 21; idx += 256) {
        int r = idx / 21, k = idx % 21;
        Xs[r][k] = (r0 + r < N_NODES) ? X[(size_t)(r0 + r) * 21 + k] : 0.f;
    }
    __syncthreads();
    if (t < 21) {
        float sa = 0.f, sd = 0.f;
        for (int f2 = 0; f2 < 128; ++f2) {
            float wv = Ws[f2][t];
            sa += wv * asrc[f2];
            sd += wv * adst[f2];
        }
        w_as[t] = sa; w_ad[t] = sd;
    }
    int f = t & 127, rsub = t >> 7;
    float Wreg[21];
#pragma unroll
    for (int k = 0; k < 21; ++k) Wreg[k] = Ws[f][k];
#pragma unroll 4
    for (int r = rsub; r < 32; r += 2) {
        if (r0 + r >= N_NODES) break;
        float a = 0.f;
#pragma unroll
        for (int k = 0; k < 21; ++k) a += Xs[r][k] * Wreg[k];
        out[(size_t)(r0 + r) * HD + f] = f2bf(a);
    }
    __syncthreads();
    if (t < 32 && r0 + t < N_NODES) {
        float sa = 0.f, sd = 0.f;
#pragma unroll
        for (int k = 0; k < 21; ++k) {
            float xv = Xs[t][k];
            sa += xv * w_as[k];
            sd += xv * w_ad[k];
        }
        alpha_s[r0 + t] = sa;
        alpha_d[r0 + t] = sd;
    }
}

// split-K GEMM body (atomic accumulate into out); W selected by fb vs F1
__device__ void dev_gemm_split(const float* __restrict__ X, const float* __restrict__ W1,
                               const float* __restrict__ W2, float* __restrict__ out,
                               int K, int F1, int Ftot, int Kc,
                               int bx, int by, int bz) {
    __shared__ float Xs[16][33];
    __shared__ float Ws[64][33];
    int t = threadIdx.x;
    int r0 = bx * 16;
    int fb = by * 64;
    const float* W = (fb < F1) ? (W1 + (size_t)fb * K) : (W2 + (size_t)(fb - F1) * K);
    int k0 = bz * Kc;
    int f = t & 63, rsub = t >> 6;
    float acc0 = 0.f, acc1 = 0.f, acc2 = 0.f, acc3 = 0.f;
    for (int kc = k0; kc < k0 + Kc; kc += 32) {
        {
            int idx = t * 2, xr = idx >> 5, xk = idx & 31;
            const float2 v = *(const float2*)&X[(size_t)(r0 + xr) * K + kc + xk];
            Xs[xr][xk] = v.x; Xs[xr][xk + 1] = v.y;
        }
        {
            int wf = t >> 2, wk = (t & 3) * 8;
            const float4* p = (const float4*)&W[(size_t)wf * K + kc + wk];
            float4 a = p[0], b = p[1];
            Ws[wf][wk] = a.x; Ws[wf][wk + 1] = a.y; Ws[wf][wk + 2] = a.z; Ws[wf][wk + 3] = a.w;
            Ws[wf][wk + 4] = b.x; Ws[wf][wk + 5] = b.y; Ws[wf][wk + 6] = b.z; Ws[wf][wk + 7] = b.w;
        }
        __syncthreads();
#pragma unroll
        for (int k = 0; k < 32; ++k) {
            float w = Ws[f][k];
            acc0 += Xs[rsub][k] * w;
            acc1 += Xs[rsub + 4][k] * w;
            acc2 += Xs[rsub + 8][k] * w;
            acc3 += Xs[rsub + 12][k] * w;
        }
        __syncthreads();
    }
    atomicAdd(&out[(size_t)(r0 + rsub) * Ftot + fb + f], acc0);
    atomicAdd(&out[(size_t)(r0 + rsub + 4) * Ftot + fb + f], acc1);
    atomicAdd(&out[(size_t)(r0 + rsub + 8) * Ftot + fb + f], acc2);
    atomicAdd(&out[(size_t)(r0 + rsub + 12) * Ftot + fb + f], acc3);
}

__global__ __launch_bounds__(256) void mega1(
        const int* __restrict__ ei, int* __restrict__ cnt,
        const float* __restrict__ x, const float* __restrict__ gat1_W,
        const float* __restrict__ gat1_as, const float* __restrict__ gat1_ad,
        unsigned short* __restrict__ h0, float* __restrict__ alpha_s, float* __restrict__ alpha_d,
        const float* __restrict__ esm, const float* __restrict__ Wih_f,
        const float* __restrict__ Wih_r, float* __restrict__ g_lstm) {
    int b = blockIdx.x;
    if (b < 256) {
        dev_hist1(ei, cnt, b);
    } else if (b < 256 + GAT1_BLKS) {
        dev_gat1(x, gat1_W, gat1_as, gat1_ad, h0, alpha_s, alpha_d, b - 256);
    } else {
        int bb = b - (256 + GAT1_BLKS);       // 0..1535 = 64 x 8 x 3
        int bx = bb & 63, by = (bb >> 6) & 7, bz = bb >> 9;
        dev_gemm_split(esm, Wih_f, Wih_r, g_lstm, ESM_DIM, 256, 512, 160, bx, by, bz);
    }
}

// ================= mega2 (@1024): scan | bounds | W conv | tab branch =================

__device__ void dev_scan4(const int4* __restrict__ in, int4* __restrict__ out, int n4) {
    __shared__ int wsum[16];
    int t = threadIdx.x, lane = t & 63, wid = t >> 6;
    int carry = 0;
    for (int base = 0; base < n4; base += 1024) {
        int i = base + t;
        int4 v = (i < n4) ? in[i] : make_int4(0, 0, 0, 0);
        int s = v.x + v.y + v.z + v.w;
        int sc = s;
#pragma unroll
        for (int off = 1; off < 64; off <<= 1) {
            int n = __shfl_up(sc, off);
            if (lane >= off) sc += n;
        }
        if (lane == 63) wsum[wid] = sc;
        __syncthreads();
        if (t < 16) {
            int xx = wsum[t];
#pragma unroll
            for (int off = 1; off < 16; off <<= 1) {
                int n = __shfl_up(xx, off);
                if (t >= off) xx += n;
            }
            wsum[t] = xx;
        }
        __syncthreads();
        int woff = wid ? wsum[wid - 1] : 0;
        int excl = carry + woff + sc - s;
        if (i < n4)
            out[i] = make_int4(excl, excl + v.x, excl + v.x + v.y, excl + v.x + v.y + v.z);
        carry += wsum[15];
        __syncthreads();
    }
}

__device__ void dev_tab(const float* __restrict__ tf, const float* __restrict__ W,
                        const float* __restrict__ bias, const float* __restrict__ g,
                        const float* __restrict__ b, float* __restrict__ z) {
    __shared__ float ssum[16][64];
    __shared__ float ssq[16][64];
    int t = threadIdx.x;
    int rg = t >> 6, j = t & 63;
    float Wj[7];
#pragma unroll
    for (int k = 0; k < 7; ++k) Wj[k] = W[j * 7 + k];
    float bj = bias[j];
    float pre[64];
    float s = 0.f, q = 0.f;
    for (int rr = 0; rr < 64; ++rr) {
        int row = rg * 64 + rr;
        const float* xp = &tf[(size_t)row * 7];
        float a = bj;
#pragma unroll
        for (int k = 0; k < 7; ++k) a += xp[k] * Wj[k];
        pre[rr] = a; s += a; q += a * a;
    }
    ssum[rg][j] = s; ssq[rg][j] = q;
    __syncthreads();
    for (int off = 8; off; off >>= 1) {
        if (rg < off) { ssum[rg][j] += ssum[rg + off][j]; ssq[rg][j] += ssq[rg + off][j]; }
        __syncthreads();
    }
    float mu = ssum[0][j] * (1.f / 1024.f);
    float var = ssq[0][j] * (1.f / 1024.f) - mu * mu;
    float sc = rsqrtf(var + 1e-5f) * g[j];
    float bb = b[j] - mu * sc;
    for (int rr = 0; rr < 64; ++rr) {
        int row = rg * 64 + rr;
        z[(size_t)row * 320 + 256 + j] = fmaxf(pre[rr] * sc + bb, 0.f);
    }
}

__global__ __launch_bounds__(1024) void mega2(
        const int* __restrict__ cnt, int* __restrict__ cntoff,
        const int* __restrict__ batch, int* __restrict__ start,
        const float* __restrict__ W, unsigned short* __restrict__ Wb,
        const float* __restrict__ tf, const float* __restrict__ tab_W,
        const float* __restrict__ tab_b, const float* __restrict__ tab_g,
        const float* __restrict__ tab_bb, float* __restrict__ z) {
    int b = blockIdx.x, t = threadIdx.x;
    if (b == 0) {
        dev_scan4((const int4*)cnt, (int4*)cntoff, NBUCK * 64);
    } else if (b < 50) {                 // graph bounds: 49 blocks x 1024
        int i = (b - 1) * 1024 + t;
        if (i >= N_NODES) return;
        int bb = batch[i];
        int bp = (i == 0) ? -1 : batch[i - 1];
        for (int g = bp + 1; g <= bb; ++g) start[g] = i;
        if (i == N_NODES - 1)
            for (int g = bb + 1; g <= NB; ++g) start[g] = N_NODES;
    } else if (b < 54) {                 // W fp32->bf16: 4 blocks x 1024 float4
        int i = (b - 50) * 1024 + t;
        float4 v = ((const float4*)W)[i];
        ((ushort4*)Wb)[i] = make_ushort4(f2bf(v.x), f2bf(v.y), f2bf(v.z), f2bf(v.w));
    } else {                             // tab branch, 1 block
        dev_tab(tf, tab_W, tab_b, tab_g, tab_bb, z);
    }
}

// ================= mega3: scatter_pairs | lstm_gate =================

__device__ __forceinline__ float sigmoidf_(float x) { return 1.f / (1.f + __expf(-x)); }

__global__ __launch_bounds__(256) void mega3(
        const int* __restrict__ ei, const int* __restrict__ cntoff, int* __restrict__ pairs,
        const float* __restrict__ g,
        const float* __restrict__ bihf, const float* __restrict__ bhhf,
        const float* __restrict__ bihr, const float* __restrict__ bhhr,
        float* __restrict__ z) {
    int b = blockIdx.x, t = threadIdx.x;
    if (b < 256) {
        __shared__ int cur[NBUCK];
        for (int u = t; u < NBUCK; u += 256) cur[u] = cntoff[u * 256 + b];
        __syncthreads();
        int e0 = b * EPB;
        int e1 = (e0 + EPB < E_TOT) ? e0 + EPB : E_TOT;
        for (int e = e0 + t; e < e1; e += 256) {
            int s, d;
            if (e < N_EDGES) { s = ei[e]; d = ei[N_EDGES + e]; }
            else             { s = d = e - N_EDGES; }
            int pos = atomicAdd(&cur[d >> 8], 1);
            pairs[pos] = s | ((d & 255) << 16);
        }
    } else {
        int idx = (b - 256) * 256 + t;
        if (idx >= NB * 128) return;
        int bb = idx >> 7, jj = idx & 127;
        int dir = jj >> 6, j = jj & 63;
        const float* gb = g + (size_t)bb * 512 + dir * 256;
        const float* bi = dir ? bihr : bihf;
        const float* bh = dir ? bhhr : bhhf;
        float gi = gb[j]       + bi[j]       + bh[j];
        float gg = gb[128 + j] + bi[128 + j] + bh[128 + j];
        float go = gb[192 + j] + bi[192 + j] + bh[192 + j];
        float c = sigmoidf_(gi) * tanhf(gg);
        z[(size_t)bb * 320 + 128 + jj] = sigmoidf_(go) * tanhf(c);
    }
}

// ================= bucket CSR (degree scan + placement) =================

__global__ void bucket_csr(const int* __restrict__ cntoff, const int* __restrict__ pairs,
                           int* __restrict__ row_ptr, int* __restrict__ csr_src) {
    __shared__ int dc[256];
    __shared__ int wt[4];
    __shared__ int cur[256];
    int b = blockIdx.x, t = threadIdx.x;
    int rs = cntoff[b * 256];
    int re = (b == NBUCK - 1) ? E_TOT : cntoff[(b + 1) * 256];
    dc[t] = 0;
    __syncthreads();
    for (int i = rs + t; i < re; i += 256) atomicAdd(&dc[pairs[i] >> 16], 1);
    __syncthreads();
    int v = dc[t];
    int lane = t & 63, wid = t >> 6;
    int sc = v;
#pragma unroll
    for (int off = 1; off < 64; off <<= 1) {
        int n = __shfl_up(sc, off);
        if (lane >= off) sc += n;
    }
    if (lane == 63) wt[wid] = sc;
    __syncthreads();
    int pref = 0;
    for (int ww = 0; ww < wid; ++ww) pref += wt[ww];
    int excl = pref + sc - v;
    int node = b * 256 + t;
    if (node <= N_NODES) row_ptr[node] = rs + excl;
    cur[t] = rs + excl;
    __syncthreads();
    for (int i = rs + t; i < re; i += 256) {
        int pk = pairs[i];
        int pos = atomicAdd(&cur[pk >> 16], 1);
        csr_src[pos] = pk & 0xFFFF;
    }
}

// ================= GAT2 linear: MFMA + fused alpha epilogue =================

__global__ __launch_bounds__(256) void gemm_mfma(const unsigned short* __restrict__ A,
                                                 const unsigned short* __restrict__ Wb,
                                                 const float* __restrict__ asrc,
                                                 const float* __restrict__ adst,
                                                 unsigned short* __restrict__ out,
                                                 float* __restrict__ alpha_s,
                                                 float* __restrict__ alpha_d, int M) {
    __shared__ unsigned short Wlds[128 * 136];
    int t = threadIdx.x;
    for (int u = t; u < 128 * 16; u += 256) {
        int row = u >> 4, seg = u & 15;
        *(ushort8*)&Wlds[row * 136 + seg * 8] = *(const ushort8*)&Wb[row * 128 + seg * 8];
    }
    __syncthreads();
    int wid = t >> 6, L = t & 63;
    int quad = L >> 4, lo = L & 15;
    int m0 = blockIdx.x * 64 + wid * 16;
    short8 afrag[4];
#pragma unroll
    for (int ch = 0; ch < 4; ++ch)
        afrag[ch] = *(const short8*)&A[(size_t)(m0 + lo) * HD + ch * 32 + quad * 8];
    float as_p[4] = {0.f, 0.f, 0.f, 0.f};
    float ad_p[4] = {0.f, 0.f, 0.f, 0.f};
#pragma unroll
    for (int ft = 0; ft < 8; ++ft) {
        f32x4 acc = {0.f, 0.f, 0.f, 0.f};
#pragma unroll
        for (int ch = 0; ch < 4; ++ch) {
            short8 b = *(const short8*)&Wlds[(ft * 16 + lo) * 136 + ch * 32 + quad * 8];
            acc = __builtin_amdgcn_mfma_f32_16x16x32_bf16(afrag[ch], b, acc, 0, 0, 0);
        }
        float asv = asrc[ft * 16 + lo];
        float adv = adst[ft * 16 + lo];
#pragma unroll
        for (int r = 0; r < 4; ++r) {
            int m = m0 + quad * 4 + r;
            if (m < M) out[(size_t)m * HD + ft * 16 + lo] = f2bf(acc[r]);
            as_p[r] += acc[r] * asv;
            ad_p[r] += acc[r] * adv;
        }
    }
#pragma unroll
    for (int off = 1; off < 16; off <<= 1) {
#pragma unroll
        for (int r = 0; r < 4; ++r) {
            as_p[r] += __shfl_xor(as_p[r], off);
            ad_p[r] += __shfl_xor(ad_p[r], off);
        }
    }
    if (lo == 0) {
#pragma unroll
        for (int r = 0; r < 4; ++r) {
            int m = m0 + quad * 4 + r;
            if (m < M) { alpha_s[m] = as_p[r]; alpha_d[m] = ad_p[r]; }
        }
    }
}

// ================= fused edge-softmax + SpMM =================
// POOL=0: write bf16 row. POOL=1: scaled atomicAdd into z[batch[w]] (mean pool fused).

template <int POOL>
__global__ void gat_spmm(const unsigned short* __restrict__ h, const int* __restrict__ row_ptr,
                         const int* __restrict__ csr_src, const float* __restrict__ alpha_s,
                         const float* __restrict__ alpha_d, const float* __restrict__ bias,
                         unsigned short* __restrict__ outp,
                         const int* __restrict__ batch, const int* __restrict__ gstart,
                         float* __restrict__ z) {
    int w = (int)((blockIdx.x * (size_t)blockDim.x + threadIdx.x) >> 6);
    int lane = threadIdx.x & 63;
    if (w >= N_NODES) return;
    int grp = lane >> 4, l16 = lane & 15;
    int rs = row_ptr[w], re = row_ptr[w + 1];
    int deg = re - rs;
    float ad = alpha_d[w];
    float acc[8] = {0.f, 0.f, 0.f, 0.f, 0.f, 0.f, 0.f, 0.f};
    if (deg <= 64) {
        int s_reg = 0;
        float e = -1e30f;
        if (lane < deg) {
            s_reg = csr_src[rs + lane];
            float t0 = alpha_s[s_reg] + ad;
            e = (t0 > 0.f) ? t0 : 0.2f * t0;
        }
        float m = e;
#pragma unroll
        for (int off = 32; off; off >>= 1) m = fmaxf(m, __shfl_xor(m, off));
        float ex = (lane < deg) ? __expf(e - m) : 0.f;
        float den = ex;
#pragma unroll
        for (int off = 32; off; off >>= 1) den += __shfl_xor(den, off);
        float coef = ex / (den + 1e-16f);
        int i = rs + grp;
        for (; i + 4 < re; i += 8) {
            int idx = i - rs;
            float c0 = __shfl(coef, idx);
            int   s0 = __shfl(s_reg, idx);
            float c1 = __shfl(coef, idx + 4);
            int   s1 = __shfl(s_reg, idx + 4);
            ushort8 h0 = *(const ushort8*)&h[(size_t)s0 * HD + l16 * 8];
            ushort8 h1 = *(const ushort8*)&h[(size_t)s1 * HD + l16 * 8];
#pragma unroll
            for (int j = 0; j < 8; ++j) acc[j] += c0 * bf2f(h0[j]);
#pragma unroll
            for (int j = 0; j < 8; ++j) acc[j] += c1 * bf2f(h1[j]);
        }
        if (i < re) {
            int idx = i - rs;
            float c0 = __shfl(coef, idx);
            int   s0 = __shfl(s_reg, idx);
            ushort8 h0 = *(const ushort8*)&h[(size_t)s0 * HD + l16 * 8];
#pragma unroll
            for (int j = 0; j < 8; ++j) acc[j] += c0 * bf2f(h0[j]);
        }
    } else {
        float m = -1e30f;
        for (int i = rs + lane; i < re; i += 64) {
            int s = csr_src[i];
            float t0 = alpha_s[s] + ad;
            t0 = (t0 > 0.f) ? t0 : 0.2f * t0;
            m = fmaxf(m, t0);
        }
#pragma unroll
        for (int off = 32; off; off >>= 1) m = fmaxf(m, __shfl_xor(m, off));
        float den = 0.f;
        for (int i = rs + lane; i < re; i += 64) {
            int s = csr_src[i];
            float t0 = alpha_s[s] + ad;
            t0 = (t0 > 0.f) ? t0 : 0.2f * t0;
            den += __expf(t0 - m);
        }
#pragma unroll
        for (int off = 32; off; off >>= 1) den += __shfl_xor(den, off);
        float inv = 1.f / (den + 1e-16f);
        for (int i = rs + grp; i < re; i += 4) {
            int s = csr_src[i];
            float t0 = alpha_s[s] + ad;
            t0 = (t0 > 0.f) ? t0 : 0.2f * t0;
            float c = __expf(t0 - m) * inv;
            ushort8 hv = *(const ushort8*)&h[(size_t)s * HD + l16 * 8];
#pragma unroll
            for (int j = 0; j < 8; ++j) acc[j] += c * bf2f(hv[j]);
        }
    }
#pragma unroll
    for (int j = 0; j < 8; ++j) {
        acc[j] += __shfl_xor(acc[j], 16);
        acc[j] += __shfl_xor(acc[j], 32);
    }
    int f0 = l16 * 8 + grp * 2;
    float2 bv = *(const float2*)&bias[f0];
    float vx = fmaxf(acc[grp * 2]     + bv.x, 0.f);
    float vy = fmaxf(acc[grp * 2 + 1] + bv.y, 0.f);
    if (POOL) {
        int g = batch[w];
        float inv = 1.f / (float)(gstart[g + 1] - gstart[g]);
        atomicAdd(&z[(size_t)g * 320 + f0], vx * inv);
        atomicAdd(&z[(size_t)g * 320 + f0 + 1], vy * inv);
    } else {
        unsigned int pv = (unsigned int)f2bf(vx) | ((unsigned int)f2bf(vy) << 16);
        *(unsigned int*)&outp[(size_t)w * HD + f0] = pv;
    }
}

// ================= fus1 split-K GEMM (global wrapper) =================

__global__ void gemm_split(const float* __restrict__ X, const float* __restrict__ W1,
                           float* __restrict__ out, int K, int Ftot, int Kc) {
    dev_gemm_split(X, W1, nullptr, out, K, Ftot, Ftot, Kc,
                   blockIdx.x, blockIdx.y, blockIdx.z);
}

// ================= BatchNorm (training stats) + relu =================

__global__ void bn_relu_cols(const float* __restrict__ in, int cols,
                             const float* __restrict__ g, const float* __restrict__ b,
                             float* __restrict__ out) {
    int j = blockIdx.x;
    int t = threadIdx.x;
    __shared__ float ssum[256], ssq[256];
    float vals[4];
    float s = 0.f, q = 0.f;
#pragma unroll
    for (int i = 0; i < 4; ++i) {
        float v = in[(size_t)(t + 256 * i) * cols + j];
        vals[i] = v; s += v; q += v * v;
    }
    ssum[t] = s; ssq[t] = q;
    __syncthreads();
    for (int off = 128; off; off >>= 1) {
        if (t < off) { ssum[t] += ssum[t + off]; ssq[t] += ssq[t + off]; }
        __syncthreads();
    }
    float mu = ssum[0] * (1.f / 1024.f);
    float var = ssq[0] * (1.f / 1024.f) - mu * mu;
    float sc = rsqrtf(var + 1e-5f) * g[j];
    float bb = b[j] - mu * sc;
#pragma unroll
    for (int i = 0; i < 4; ++i) {
        float v = vals[i] * sc + bb;
        out[(size_t)(t + 256 * i) * cols + j] = fmaxf(v, 0.f);
    }
}

// ================= fus2 + final fused: out = relu(z1@W2^T + b2) @ W3^T + b3 =================
// 64 blocks x 256 thr; block = 16 rows x all 128 cols; K=256

__global__ __launch_bounds__(256) void fus2_final(const float* __restrict__ z1,
                                                  const float* __restrict__ W2,
                                                  const float* __restrict__ b2,
                                                  const float* __restrict__ W3,
                                                  const float* __restrict__ b3,
                                                  float* __restrict__ out) {
    __shared__ float Xs[16][33];
    __shared__ float Ws[128][33];
    __shared__ float rowsum[16];
    int t = threadIdx.x;
    int r0 = blockIdx.x * 16;
    int f = t & 127, rh = t >> 7;   // rh in {0,1}
    float acc[8] = {0.f, 0.f, 0.f, 0.f, 0.f, 0.f, 0.f, 0.f};
    for (int kc = 0; kc < 256; kc += 32) {
        {
            int idx = t * 2, xr = idx >> 5, xk = idx & 31;
            *(float2*)&Xs[xr][xk] = *(const float2*)&z1[(size_t)(r0 + xr) * 256 + kc + xk];
        }
#pragma unroll
        for (int i = 0; i < 4; ++i) {
            int id2 = t + 256 * i;
            int wf = id2 >> 3, wk = (id2 & 7) * 4;
            *(float4*)&Ws[wf][wk] = *(const float4*)&W2[(size_t)wf * 256 + kc + wk];
        }
        __syncthreads();
#pragma unroll
        for (int k = 0; k < 32; ++k) {
            float w = Ws[f][k];
#pragma unroll
            for (int r = 0; r < 8; ++r) acc[r] += Xs[rh * 8 + r][k] * w;
        }
        __syncthreads();
    }
    float bv = b2[f], wv = W3[f];
    if (t < 16) rowsum[t] = 0.f;
    __syncthreads();
#pragma unroll
    for (int r = 0; r < 8; ++r) {
        float v = fmaxf(acc[r] + bv, 0.f) * wv;
#pragma unroll
        for (int off = 32; off; off >>= 1) v += __shfl_xor(v, off);
        if ((t & 63) == 0) atomicAdd(&rowsum[rh * 8 + r], v);
    }
    __syncthreads();
    if (t < 16) out[r0 + t] = rowsum[t] + b3[0];
}

// ================= launch =================

extern "C" void kernel_launch(void* const* d_in, const int* in_sizes, int n_in,
                              void* d_out, int out_size, void* d_ws, size_t ws_size,
                              hipStream_t stream) {
    const float* x        = (const float*)d_in[0];
    const int*   ei       = (const int*)d_in[1];
    const int*   batch    = (const int*)d_in[2];
    const float* esm      = (const float*)d_in[3];
    const float* tabf     = (const float*)d_in[4];
    const float* gat1_W   = (const float*)d_in[5];
    const float* gat1_as  = (const float*)d_in[6];
    const float* gat1_ad  = (const float*)d_in[7];
    const float* gat1_b   = (const float*)d_in[8];
    const float* gat2_W   = (const float*)d_in[9];
    const float* gat2_as  = (const float*)d_in[10];
    const float* gat2_ad  = (const float*)d_in[11];
    const float* gat2_b   = (const float*)d_in[12];
    const float* Wih_f    = (const float*)d_in[13];
    const float* bih_f    = (const float*)d_in[15];
    const float* bhh_f    = (const float*)d_in[16];
    const float* Wih_r    = (const float*)d_in[17];
    const float* bih_r    = (const float*)d_in[19];
    const float* bhh_r    = (const float*)d_in[20];
    const float* tab_W    = (const float*)d_in[21];
    const float* tab_b    = (const float*)d_in[22];
    const float* tab_g    = (const float*)d_in[23];
    const float* tab_bb   = (const float*)d_in[24];
    const float* fus1_W   = (const float*)d_in[25];
    const float* fus_g    = (const float*)d_in[27];
    const float* fus_bb   = (const float*)d_in[28];
    const float* fus2_W   = (const float*)d_in[29];
    const float* fus2_b   = (const float*)d_in[30];
    const float* fus3_W   = (const float*)d_in[31];
    const float* fus3_b   = (const float*)d_in[32];
    float* out = (float*)d_out;

    char* ws = (char*)d_ws;
    size_t off = 0;
    auto alloc = [&](size_t bytes) -> char* {
        char* p = ws + off;
        off += (bytes + 255) & ~(size_t)255;
        return p;
    };
    unsigned short* h0_bf = (unsigned short*)alloc((size_t)N_PAD * HD * 2);
    unsigned short* hA_bf = (unsigned short*)alloc((size_t)N_PAD * HD * 2);
    unsigned short* h2_bf = (unsigned short*)alloc((size_t)N_PAD * HD * 2);
    float* alpha_s = (float*)alloc((size_t)N_NODES * 4);
    float* alpha_d = (float*)alloc((size_t)N_NODES * 4);
    unsigned short* w2bf = (unsigned short*)alloc((size_t)HD * HD * 2);
    int*   row_ptr = (int*)alloc((size_t)(N_NODES + 1) * 4);
    int*   csr_src = (int*)alloc((size_t)E_TOT * 4);
    int*   pairs   = (int*)alloc((size_t)E_TOT * 4);
    int*   cnt     = (int*)alloc((size_t)NBUCK * 256 * 4);
    int*   cntoff  = (int*)alloc((size_t)NBUCK * 256 * 4);
    int*   gstart  = (int*)alloc((size_t)(NB + 1) * 4);
    float* z1      = (float*)alloc((size_t)NB * 256 * 4);
    // zero-init group (contiguous, one memset): z (pool atomics), g_lstm, z1pre
    float* z       = (float*)alloc((size_t)NB * 320 * 4);
    float* g_lstm  = (float*)alloc((size_t)NB * 512 * 4);
    float* z1pre   = (float*)alloc((size_t)NB * 256 * 4);
    size_t zero_len = (size_t)((char*)z1pre + (size_t)NB * 256 * 4 - (char*)z);
    hipMemsetAsync(z, 0, zero_len, stream);

    // 1) independent front: hist | gat1 linear+alphas | LSTM GEMM
    mega1<<<256 + GAT1_BLKS + 1536, 256, 0, stream>>>(
        ei, cnt, x, gat1_W, gat1_as, gat1_ad, h0_bf, alpha_s, alpha_d,
        esm, Wih_f, Wih_r, g_lstm);

    // 2) scan | graph bounds | W->bf16 | tab branch
    mega2<<<55, 1024, 0, stream>>>(cnt, cntoff, batch, gstart, gat2_W, w2bf,
                                   tabf, tab_W, tab_b, tab_g, tab_bb, z);

    // 3) scatter pairs | LSTM nonlinearity
    mega3<<<256 + 512, 256, 0, stream>>>(ei, cntoff, pairs,
                                         g_lstm, bih_f, bhh_f, bih_r, bhh_r, z);

    // 4) CSR finalize
    bucket_csr<<<NBUCK, 256, 0, stream>>>(cntoff, pairs, row_ptr, csr_src);

    int aggGrid = (N_NODES + 3) / 4;

    // 5) GAT layer 1 aggregation
    gat_spmm<0><<<aggGrid, 256, 0, stream>>>(h0_bf, row_ptr, csr_src, alpha_s, alpha_d,
                                             gat1_b, hA_bf, nullptr, nullptr, nullptr);

    // 6) GAT2 linear (MFMA, alphas fused)
    gemm_mfma<<<N_PAD / 64, 256, 0, stream>>>(hA_bf, w2bf, gat2_as, gat2_ad,
                                              h2_bf, alpha_s, alpha_d, N_NODES);

    // 7) GAT layer 2 aggregation + fused mean pool (atomics into z[:, :128))
    gat_spmm<1><<<aggGrid, 256, 0, stream>>>(h2_bf, row_ptr, csr_src, alpha_s, alpha_d,
                                             gat2_b, nullptr, batch, gstart, z);

    // 8) fusion head
    gemm_split<<<dim3(64, 4, 2), 256, 0, stream>>>(z, fus1_W, z1pre, 320, 256, 160);
    bn_relu_cols<<<256, 256, 0, stream>>>(z1pre, 256, fus_g, fus_bb, z1);
    fus2_final<<<64, 256, 0, stream>>>(z1, fus2_W, fus2_b, fus3_W, fus3_b, out);

    (void)in_sizes; (void)n_in; (void)out_size; (void)ws_size;
}

// Round 8
// 320.307 us; speedup vs baseline: 1.1929x; 1.1929x over previous
//
#include <hip/hip_runtime.h>
#include <hip/hip_bf16.h>

#define N_NODES 50000
#define N_PAD   50048
#define N_EDGES 800000
#define E_TOT   850000
#define NB      1024
#define ESM_DIM 480
#define HD      128
#define NBUCK   196          // buckets of 256 dst nodes
#define CAP     5120         // fixed bucket capacity (mean 4352 + 12 sigma)
#define EPB     3321         // edges per scatter block (256 blocks)
#define SC_BLK  256
#define G1_BLK  1563
#define LSTM_BLK 1536
#define BND_BLK 196
#define WC_BLK  16
#define TAB_BLK 4

typedef short short8 __attribute__((ext_vector_type(8)));
typedef unsigned short ushort8 __attribute__((ext_vector_type(8)));
typedef float f32x4 __attribute__((ext_vector_type(4)));

__device__ __forceinline__ float bf2f(unsigned int u) {
    union { unsigned int i; float f; } c; c.i = u << 16; return c.f;
}
__device__ __forceinline__ unsigned short f2bf(float f) {
    union { float f; unsigned int i; } c; c.f = f;
    unsigned int i = c.i;
    return (unsigned short)((i + 0x7FFFu + ((i >> 16) & 1u)) >> 16);
}

// ================= megaA parts =================

// scatter with per-block LDS count + global range reservation (no hist/scan stages)
__device__ void dev_scatter(const int* __restrict__ ei, int* __restrict__ gcur,
                            int* __restrict__ pairs, int blk) {
    __shared__ int hist[NBUCK];
    int t = threadIdx.x;
    for (int u = t; u < NBUCK; u += 256) hist[u] = 0;
    __syncthreads();
    int e0 = blk * EPB;
    int e1 = (e0 + EPB < E_TOT) ? e0 + EPB : E_TOT;
    for (int e = e0 + t; e < e1; e += 256) {
        int d = (e < N_EDGES) ? ei[N_EDGES + e] : (e - N_EDGES);
        atomicAdd(&hist[d >> 8], 1);
    }
    __syncthreads();
    for (int u = t; u < NBUCK; u += 256) {
        int c = hist[u];
        hist[u] = (c > 0) ? atomicAdd(&gcur[u], c) : 0;   // base within bucket
    }
    __syncthreads();
    for (int e = e0 + t; e < e1; e += 256) {
        int s, d;
        if (e < N_EDGES) { s = ei[e]; d = ei[N_EDGES + e]; }
        else             { s = d = e - N_EDGES; }
        int bu = d >> 8;
        int pos = atomicAdd(&hist[bu], 1);
        pairs[bu * CAP + pos] = s | ((d & 255) << 16);    // s < 65536
    }
}

__device__ void dev_gat1(const float* __restrict__ X, const float* __restrict__ W,
                         const float* __restrict__ asrc, const float* __restrict__ adst,
                         unsigned short* __restrict__ out,
                         float* __restrict__ alpha_s, float* __restrict__ alpha_d, int blk) {
    __shared__ float Xs[32][23];
    __shared__ float Ws[128][21];
    __shared__ float w_as[21], w_ad[21];
    int t = threadIdx.x;
    int r0 = blk * 32;
    for (int idx = t; idx < 128 * 21; idx += 256) Ws[idx / 21][idx % 21] = W[idx];
    for (int idx = t; idx < 32 * 21; idx += 256) {
        int r = idx / 21, k = idx % 21;
        Xs[r][k] = (r0 + r < N_NODES) ? X[(size_t)(r0 + r) * 21 + k] : 0.f;
    }
    __syncthreads();
    if (t < 21) {
        float sa = 0.f, sd = 0.f;
        for (int f2 = 0; f2 < 128; ++f2) {
            float wv = Ws[f2][t];
            sa += wv * asrc[f2];
            sd += wv * adst[f2];
        }
        w_as[t] = sa; w_ad[t] = sd;
    }
    int f = t & 127, rsub = t >> 7;
    float Wreg[21];
#pragma unroll
    for (int k = 0; k < 21; ++k) Wreg[k] = Ws[f][k];
#pragma unroll 4
    for (int r = rsub; r < 32; r += 2) {
        if (r0 + r >= N_NODES) break;
        float a = 0.f;
#pragma unroll
        for (int k = 0; k < 21; ++k) a += Xs[r][k] * Wreg[k];
        out[(size_t)(r0 + r) * HD + f] = f2bf(a);
    }
    __syncthreads();
    if (t < 32 && r0 + t < N_NODES) {
        float sa = 0.f, sd = 0.f;
#pragma unroll
        for (int k = 0; k < 21; ++k) {
            float xv = Xs[t][k];
            sa += xv * w_as[k];
            sd += xv * w_ad[k];
        }
        alpha_s[r0 + t] = sa;
        alpha_d[r0 + t] = sd;
    }
}

// split-K GEMM body (atomic accumulate), used for LSTM gates
__device__ void dev_gemm_split(const float* __restrict__ X, const float* __restrict__ W1,
                               const float* __restrict__ W2, float* __restrict__ out,
                               int K, int F1, int Ftot, int Kc,
                               int bx, int by, int bz) {
    __shared__ float Xs[16][33];
    __shared__ float Ws[64][33];
    int t = threadIdx.x;
    int r0 = bx * 16;
    int fb = by * 64;
    const float* W = (fb < F1) ? (W1 + (size_t)fb * K) : (W2 + (size_t)(fb - F1) * K);
    int k0 = bz * Kc;
    int f = t & 63, rsub = t >> 6;
    float acc0 = 0.f, acc1 = 0.f, acc2 = 0.f, acc3 = 0.f;
    for (int kc = k0; kc < k0 + Kc; kc += 32) {
        {
            int idx = t * 2, xr = idx >> 5, xk = idx & 31;
            const float2 v = *(const float2*)&X[(size_t)(r0 + xr) * K + kc + xk];
            Xs[xr][xk] = v.x; Xs[xr][xk + 1] = v.y;
        }
        {
            int wf = t >> 2, wk = (t & 3) * 8;
            const float4* p = (const float4*)&W[(size_t)wf * K + kc + wk];
            float4 a = p[0], b = p[1];
            Ws[wf][wk] = a.x; Ws[wf][wk + 1] = a.y; Ws[wf][wk + 2] = a.z; Ws[wf][wk + 3] = a.w;
            Ws[wf][wk + 4] = b.x; Ws[wf][wk + 5] = b.y; Ws[wf][wk + 6] = b.z; Ws[wf][wk + 7] = b.w;
        }
        __syncthreads();
#pragma unroll
        for (int k = 0; k < 32; ++k) {
            float w = Ws[f][k];
            acc0 += Xs[rsub][k] * w;
            acc1 += Xs[rsub + 4][k] * w;
            acc2 += Xs[rsub + 8][k] * w;
            acc3 += Xs[rsub + 12][k] * w;
        }
        __syncthreads();
    }
    atomicAdd(&out[(size_t)(r0 + rsub) * Ftot + fb + f], acc0);
    atomicAdd(&out[(size_t)(r0 + rsub + 4) * Ftot + fb + f], acc1);
    atomicAdd(&out[(size_t)(r0 + rsub + 8) * Ftot + fb + f], acc2);
    atomicAdd(&out[(size_t)(r0 + rsub + 12) * Ftot + fb + f], acc3);
}

// tab branch: 4 blocks x 256 thr, block handles 16 cols; recompute (no big reg array)
__device__ void dev_tab4(const float* __restrict__ tf, const float* __restrict__ W,
                         const float* __restrict__ bias, const float* __restrict__ g,
                         const float* __restrict__ b, float* __restrict__ z, int blk) {
    __shared__ float ssum[16][16];
    __shared__ float ssq[16][16];
    int t = threadIdx.x;
    int rg = t >> 4, jl = t & 15;
    int j = blk * 16 + jl;
    float Wj[7];
#pragma unroll
    for (int k = 0; k < 7; ++k) Wj[k] = W[j * 7 + k];
    float bj = bias[j];
    float s = 0.f, q = 0.f;
    for (int rr = 0; rr < 64; ++rr) {
        int row = rg * 64 + rr;
        const float* xp = &tf[(size_t)row * 7];
        float a = bj;
#pragma unroll
        for (int k = 0; k < 7; ++k) a += xp[k] * Wj[k];
        s += a; q += a * a;
    }
    ssum[rg][jl] = s; ssq[rg][jl] = q;
    __syncthreads();
    for (int off = 8; off; off >>= 1) {
        if (rg < off) { ssum[rg][jl] += ssum[rg + off][jl]; ssq[rg][jl] += ssq[rg + off][jl]; }
        __syncthreads();
    }
    float mu = ssum[0][jl] * (1.f / 1024.f);
    float var = ssq[0][jl] * (1.f / 1024.f) - mu * mu;
    float sc = rsqrtf(var + 1e-5f) * g[j];
    float sh = b[j] - mu * sc;
    for (int rr = 0; rr < 64; ++rr) {
        int row = rg * 64 + rr;
        const float* xp = &tf[(size_t)row * 7];
        float a = bj;
#pragma unroll
        for (int k = 0; k < 7; ++k) a += xp[k] * Wj[k];
        z[(size_t)row * 320 + 256 + j] = fmaxf(a * sc + sh, 0.f);
    }
}

__global__ __launch_bounds__(256) void megaA(
        const int* __restrict__ ei, int* __restrict__ gcur, int* __restrict__ pairs,
        const float* __restrict__ x, const float* __restrict__ gat1_W,
        const float* __restrict__ gat1_as, const float* __restrict__ gat1_ad,
        unsigned short* __restrict__ h0, float* __restrict__ alpha_s, float* __restrict__ alpha_d,
        const float* __restrict__ esm, const float* __restrict__ Wih_f,
        const float* __restrict__ Wih_r, float* __restrict__ g_lstm,
        const int* __restrict__ batch, int* __restrict__ gstart,
        const float* __restrict__ W2, unsigned short* __restrict__ Wb,
        const float* __restrict__ tf, const float* __restrict__ tab_W,
        const float* __restrict__ tab_b, const float* __restrict__ tab_g,
        const float* __restrict__ tab_bb, float* __restrict__ z) {
    int b = blockIdx.x, t = threadIdx.x;
    if (b < SC_BLK) {
        dev_scatter(ei, gcur, pairs, b);
    } else if (b < SC_BLK + G1_BLK) {
        dev_gat1(x, gat1_W, gat1_as, gat1_ad, h0, alpha_s, alpha_d, b - SC_BLK);
    } else if (b < SC_BLK + G1_BLK + LSTM_BLK) {
        int bb = b - (SC_BLK + G1_BLK);       // 64 x 8 x 3
        dev_gemm_split(esm, Wih_f, Wih_r, g_lstm, ESM_DIM, 256, 512, 160,
                       bb & 63, (bb >> 6) & 7, bb >> 9);
    } else if (b < SC_BLK + G1_BLK + LSTM_BLK + BND_BLK) {
        int i = (b - (SC_BLK + G1_BLK + LSTM_BLK)) * 256 + t;
        if (i >= N_NODES) return;
        int bb = batch[i];
        int bp = (i == 0) ? -1 : batch[i - 1];
        for (int g = bp + 1; g <= bb; ++g) gstart[g] = i;
        if (i == N_NODES - 1)
            for (int g = bb + 1; g <= NB; ++g) gstart[g] = N_NODES;
    } else if (b < SC_BLK + G1_BLK + LSTM_BLK + BND_BLK + WC_BLK) {
        int i = (b - (SC_BLK + G1_BLK + LSTM_BLK + BND_BLK)) * 256 + t;
        if (i >= 128 * 32) return;
        float4 v = ((const float4*)W2)[i];
        ((ushort4*)Wb)[i] = make_ushort4(f2bf(v.x), f2bf(v.y), f2bf(v.z), f2bf(v.w));
    } else {
        dev_tab4(tf, tab_W, tab_b, tab_g, tab_bb, z,
                 b - (SC_BLK + G1_BLK + LSTM_BLK + BND_BLK + WC_BLK));
    }
}

// ================= megaB: bucket CSR | LSTM nonlinearity =================

__device__ __forceinline__ float sigmoidf_(float x) { return 1.f / (1.f + __expf(-x)); }

__global__ __launch_bounds__(256) void megaB(
        const int* __restrict__ gcur, const int* __restrict__ pairs,
        int* __restrict__ row_beg, int* __restrict__ row_end, int* __restrict__ csr_src,
        const float* __restrict__ g,
        const float* __restrict__ bihf, const float* __restrict__ bhhf,
        const float* __restrict__ bihr, const float* __restrict__ bhhr,
        float* __restrict__ z) {
    int b = blockIdx.x, t = threadIdx.x;
    if (b < NBUCK) {
        __shared__ int dc[256];
        __shared__ int wt[4];
        __shared__ int cur[256];
        int rs = b * CAP;
        int re = rs + gcur[b];
        dc[t] = 0;
        __syncthreads();
        for (int i = rs + t; i < re; i += 256) atomicAdd(&dc[pairs[i] >> 16], 1);
        __syncthreads();
        int v = dc[t];
        int lane = t & 63, wid = t >> 6;
        int sc = v;
#pragma unroll
        for (int off = 1; off < 64; off <<= 1) {
            int n = __shfl_up(sc, off);
            if (lane >= off) sc += n;
        }
        if (lane == 63) wt[wid] = sc;
        __syncthreads();
        int pref = 0;
        for (int ww = 0; ww < wid; ++ww) pref += wt[ww];
        int beg = rs + pref + sc - v;
        int node = b * 256 + t;
        if (node < N_NODES) { row_beg[node] = beg; row_end[node] = beg + v; }
        cur[t] = beg;
        __syncthreads();
        for (int i = rs + t; i < re; i += 256) {
            int pk = pairs[i];
            int pos = atomicAdd(&cur[pk >> 16], 1);
            csr_src[pos] = pk & 0xFFFF;
        }
    } else {
        int idx = (b - NBUCK) * 256 + t;
        if (idx >= NB * 128) return;
        int bb = idx >> 7, jj = idx & 127;
        int dir = jj >> 6, j = jj & 63;
        const float* gb = g + (size_t)bb * 512 + dir * 256;
        const float* bi = dir ? bihr : bihf;
        const float* bh = dir ? bhhr : bhhf;
        float gi = gb[j]       + bi[j]       + bh[j];
        float gg = gb[128 + j] + bi[128 + j] + bh[128 + j];
        float go = gb[192 + j] + bi[192 + j] + bh[192 + j];
        float c = sigmoidf_(gi) * tanhf(gg);
        z[(size_t)bb * 320 + 128 + jj] = sigmoidf_(go) * tanhf(c);
    }
}

// ================= GAT2 linear: MFMA + fused alpha epilogue =================

__global__ __launch_bounds__(256) void gemm_mfma(const unsigned short* __restrict__ A,
                                                 const unsigned short* __restrict__ Wb,
                                                 const float* __restrict__ asrc,
                                                 const float* __restrict__ adst,
                                                 unsigned short* __restrict__ out,
                                                 float* __restrict__ alpha_s,
                                                 float* __restrict__ alpha_d, int M) {
    __shared__ unsigned short Wlds[128 * 136];
    int t = threadIdx.x;
    for (int u = t; u < 128 * 16; u += 256) {
        int row = u >> 4, seg = u & 15;
        *(ushort8*)&Wlds[row * 136 + seg * 8] = *(const ushort8*)&Wb[row * 128 + seg * 8];
    }
    __syncthreads();
    int wid = t >> 6, L = t & 63;
    int quad = L >> 4, lo = L & 15;
    int m0 = blockIdx.x * 64 + wid * 16;
    short8 afrag[4];
#pragma unroll
    for (int ch = 0; ch < 4; ++ch)
        afrag[ch] = *(const short8*)&A[(size_t)(m0 + lo) * HD + ch * 32 + quad * 8];
    float as_p[4] = {0.f, 0.f, 0.f, 0.f};
    float ad_p[4] = {0.f, 0.f, 0.f, 0.f};
#pragma unroll
    for (int ft = 0; ft < 8; ++ft) {
        f32x4 acc = {0.f, 0.f, 0.f, 0.f};
#pragma unroll
        for (int ch = 0; ch < 4; ++ch) {
            short8 b = *(const short8*)&Wlds[(ft * 16 + lo) * 136 + ch * 32 + quad * 8];
            acc = __builtin_amdgcn_mfma_f32_16x16x32_bf16(afrag[ch], b, acc, 0, 0, 0);
        }
        float asv = asrc[ft * 16 + lo];
        float adv = adst[ft * 16 + lo];
#pragma unroll
        for (int r = 0; r < 4; ++r) {
            int m = m0 + quad * 4 + r;
            if (m < M) out[(size_t)m * HD + ft * 16 + lo] = f2bf(acc[r]);
            as_p[r] += acc[r] * asv;
            ad_p[r] += acc[r] * adv;
        }
    }
#pragma unroll
    for (int off = 1; off < 16; off <<= 1) {
#pragma unroll
        for (int r = 0; r < 4; ++r) {
            as_p[r] += __shfl_xor(as_p[r], off);
            ad_p[r] += __shfl_xor(ad_p[r], off);
        }
    }
    if (lo == 0) {
#pragma unroll
        for (int r = 0; r < 4; ++r) {
            int m = m0 + quad * 4 + r;
            if (m < M) { alpha_s[m] = as_p[r]; alpha_d[m] = ad_p[r]; }
        }
    }
}

// ================= fused edge-softmax + SpMM (wave per dst) =================

__global__ void gat_spmm(const unsigned short* __restrict__ h, const int* __restrict__ row_beg,
                         const int* __restrict__ row_end, const int* __restrict__ csr_src,
                         const float* __restrict__ alpha_s, const float* __restrict__ alpha_d,
                         const float* __restrict__ bias, unsigned short* __restrict__ outp) {
    int w = (int)((blockIdx.x * (size_t)blockDim.x + threadIdx.x) >> 6);
    int lane = threadIdx.x & 63;
    if (w >= N_NODES) return;
    int grp = lane >> 4, l16 = lane & 15;
    int rs = row_beg[w], re = row_end[w];
    int deg = re - rs;
    float ad = alpha_d[w];
    float acc[8] = {0.f, 0.f, 0.f, 0.f, 0.f, 0.f, 0.f, 0.f};
    if (deg <= 64) {
        int s_reg = 0;
        float e = -1e30f;
        if (lane < deg) {
            s_reg = csr_src[rs + lane];
            float t0 = alpha_s[s_reg] + ad;
            e = (t0 > 0.f) ? t0 : 0.2f * t0;
        }
        float m = e;
#pragma unroll
        for (int off = 32; off; off >>= 1) m = fmaxf(m, __shfl_xor(m, off));
        float ex = (lane < deg) ? __expf(e - m) : 0.f;
        float den = ex;
#pragma unroll
        for (int off = 32; off; off >>= 1) den += __shfl_xor(den, off);
        float coef = ex / (den + 1e-16f);
        int i = rs + grp;
        for (; i + 4 < re; i += 8) {
            int idx = i - rs;
            float c0 = __shfl(coef, idx);
            int   s0 = __shfl(s_reg, idx);
            float c1 = __shfl(coef, idx + 4);
            int   s1 = __shfl(s_reg, idx + 4);
            ushort8 h0 = *(const ushort8*)&h[(size_t)s0 * HD + l16 * 8];
            ushort8 h1 = *(const ushort8*)&h[(size_t)s1 * HD + l16 * 8];
#pragma unroll
            for (int j = 0; j < 8; ++j) acc[j] += c0 * bf2f(h0[j]);
#pragma unroll
            for (int j = 0; j < 8; ++j) acc[j] += c1 * bf2f(h1[j]);
        }
        if (i < re) {
            int idx = i - rs;
            float c0 = __shfl(coef, idx);
            int   s0 = __shfl(s_reg, idx);
            ushort8 h0 = *(const ushort8*)&h[(size_t)s0 * HD + l16 * 8];
#pragma unroll
            for (int j = 0; j < 8; ++j) acc[j] += c0 * bf2f(h0[j]);
        }
    } else {
        float m = -1e30f;
        for (int i = rs + lane; i < re; i += 64) {
            int s = csr_src[i];
            float t0 = alpha_s[s] + ad;
            t0 = (t0 > 0.f) ? t0 : 0.2f * t0;
            m = fmaxf(m, t0);
        }
#pragma unroll
        for (int off = 32; off; off >>= 1) m = fmaxf(m, __shfl_xor(m, off));
        float den = 0.f;
        for (int i = rs + lane; i < re; i += 64) {
            int s = csr_src[i];
            float t0 = alpha_s[s] + ad;
            t0 = (t0 > 0.f) ? t0 : 0.2f * t0;
            den += __expf(t0 - m);
        }
#pragma unroll
        for (int off = 32; off; off >>= 1) den += __shfl_xor(den, off);
        float inv = 1.f / (den + 1e-16f);
        for (int i = rs + grp; i < re; i += 4) {
            int s = csr_src[i];
            float t0 = alpha_s[s] + ad;
            t0 = (t0 > 0.f) ? t0 : 0.2f * t0;
            float c = __expf(t0 - m) * inv;
            ushort8 hv = *(const ushort8*)&h[(size_t)s * HD + l16 * 8];
#pragma unroll
            for (int j = 0; j < 8; ++j) acc[j] += c * bf2f(hv[j]);
        }
    }
#pragma unroll
    for (int j = 0; j < 8; ++j) {
        acc[j] += __shfl_xor(acc[j], 16);
        acc[j] += __shfl_xor(acc[j], 32);
    }
    int f0 = l16 * 8 + grp * 2;
    float2 bv = *(const float2*)&bias[f0];
    float vx = fmaxf(acc[grp * 2]     + bv.x, 0.f);
    float vy = fmaxf(acc[grp * 2 + 1] + bv.y, 0.f);
    unsigned int pv = (unsigned int)f2bf(vx) | ((unsigned int)f2bf(vy) << 16);
    *(unsigned int*)&outp[(size_t)w * HD + f0] = pv;
}

// ================= mean pool per graph (bf16 in, 2x node ILP) =================

__global__ void pool_kernel(const unsigned short* __restrict__ h, const int* __restrict__ start,
                            float* __restrict__ z) {
    int w = (int)((blockIdx.x * (size_t)blockDim.x + threadIdx.x) >> 6);
    int lane = threadIdx.x & 63;
    if (w >= NB) return;
    int grp = lane >> 4, l16 = lane & 15;
    int s0 = start[w], s1 = start[w + 1];
    float acc[8] = {0.f, 0.f, 0.f, 0.f, 0.f, 0.f, 0.f, 0.f};
    int n = s0 + grp;
    for (; n + 4 < s1; n += 8) {
        ushort8 a = *(const ushort8*)&h[(size_t)n * HD + l16 * 8];
        ushort8 b = *(const ushort8*)&h[(size_t)(n + 4) * HD + l16 * 8];
#pragma unroll
        for (int j = 0; j < 8; ++j) acc[j] += bf2f(a[j]);
#pragma unroll
        for (int j = 0; j < 8; ++j) acc[j] += bf2f(b[j]);
    }
    if (n < s1) {
        ushort8 a = *(const ushort8*)&h[(size_t)n * HD + l16 * 8];
#pragma unroll
        for (int j = 0; j < 8; ++j) acc[j] += bf2f(a[j]);
    }
#pragma unroll
    for (int j = 0; j < 8; ++j) {
        acc[j] += __shfl_xor(acc[j], 16);
        acc[j] += __shfl_xor(acc[j], 32);
    }
    float inv = 1.f / fmaxf((float)(s1 - s0), 1.f);
    int f0 = l16 * 8 + grp * 2;
    *(float2*)&z[(size_t)w * 320 + f0] =
        make_float2(acc[grp * 2] * inv, acc[grp * 2 + 1] * inv);
}

// ================= fus1: z1pre = z @ fus1_W^T (no bias; cancels in BN) + column stats =================
// grid (64,4) x 256 thr: 16 rows x 64 cols, K=320 full

__global__ __launch_bounds__(256) void fus1_stats(const float* __restrict__ X,
                                                  const float* __restrict__ W1,
                                                  float* __restrict__ out,
                                                  float* __restrict__ colsum,
                                                  float* __restrict__ colsq) {
    __shared__ float Xs[16][33];
    __shared__ float Ws[64][33];
    __shared__ float cs[4][64];
    __shared__ float cq[4][64];
    int t = threadIdx.x;
    int r0 = blockIdx.x * 16;
    int fb = blockIdx.y * 64;
    const float* W = W1 + (size_t)fb * 320;
    int f = t & 63, rsub = t >> 6;
    float acc0 = 0.f, acc1 = 0.f, acc2 = 0.f, acc3 = 0.f;
    for (int kc = 0; kc < 320; kc += 32) {
        {
            int idx = t * 2, xr = idx >> 5, xk = idx & 31;
            const float2 v = *(const float2*)&X[(size_t)(r0 + xr) * 320 + kc + xk];
            Xs[xr][xk] = v.x; Xs[xr][xk + 1] = v.y;
        }
        {
            int wf = t >> 2, wk = (t & 3) * 8;
            const float4* p = (const float4*)&W[(size_t)wf * 320 + kc + wk];
            float4 a = p[0], b = p[1];
            Ws[wf][wk] = a.x; Ws[wf][wk + 1] = a.y; Ws[wf][wk + 2] = a.z; Ws[wf][wk + 3] = a.w;
            Ws[wf][wk + 4] = b.x; Ws[wf][wk + 5] = b.y; Ws[wf][wk + 6] = b.z; Ws[wf][wk + 7] = b.w;
        }
        __syncthreads();
#pragma unroll
        for (int k = 0; k < 32; ++k) {
            float w = Ws[f][k];
            acc0 += Xs[rsub][k] * w;
            acc1 += Xs[rsub + 4][k] * w;
            acc2 += Xs[rsub + 8][k] * w;
            acc3 += Xs[rsub + 12][k] * w;
        }
        __syncthreads();
    }
    out[(size_t)(r0 + rsub) * 256 + fb + f] = acc0;
    out[(size_t)(r0 + rsub + 4) * 256 + fb + f] = acc1;
    out[(size_t)(r0 + rsub + 8) * 256 + fb + f] = acc2;
    out[(size_t)(r0 + rsub + 12) * 256 + fb + f] = acc3;
    cs[rsub][f] = acc0 + acc1 + acc2 + acc3;
    cq[rsub][f] = acc0 * acc0 + acc1 * acc1 + acc2 * acc2 + acc3 * acc3;
    __syncthreads();
    if (rsub == 0) {
        atomicAdd(&colsum[fb + f], cs[0][f] + cs[1][f] + cs[2][f] + cs[3][f]);
        atomicAdd(&colsq[fb + f],  cq[0][f] + cq[1][f] + cq[2][f] + cq[3][f]);
    }
}

// ================= fus2+final with BN inline =================
// out = relu(bn(z1pre) ) @ ... : 64 blocks x 256 thr, 16 rows x 128 cols, K=256

__global__ __launch_bounds__(256) void fus2_final(const float* __restrict__ z1pre,
                                                  const float* __restrict__ colsum,
                                                  const float* __restrict__ colsq,
                                                  const float* __restrict__ fus_g,
                                                  const float* __restrict__ fus_bb,
                                                  const float* __restrict__ W2,
                                                  const float* __restrict__ b2,
                                                  const float* __restrict__ W3,
                                                  const float* __restrict__ b3,
                                                  float* __restrict__ out) {
    __shared__ float Xs[16][33];
    __shared__ float Ws[128][33];
    __shared__ float rowsum[16];
    __shared__ float sc_[256], sh_[256];
    int t = threadIdx.x;
    {
        float mu = colsum[t] * (1.f / 1024.f);
        float var = colsq[t] * (1.f / 1024.f) - mu * mu;
        float s = rsqrtf(var + 1e-5f) * fus_g[t];
        sc_[t] = s;
        sh_[t] = fus_bb[t] - mu * s;
    }
    __syncthreads();
    int r0 = blockIdx.x * 16;
    int f = t & 127, rh = t >> 7;
    float acc[8] = {0.f, 0.f, 0.f, 0.f, 0.f, 0.f, 0.f, 0.f};
    for (int kc = 0; kc < 256; kc += 32) {
        {
            int idx = t * 2, xr = idx >> 5, xk = idx & 31;
            float2 v = *(const float2*)&z1pre[(size_t)(r0 + xr) * 256 + kc + xk];
            Xs[xr][xk]     = fmaxf(v.x * sc_[kc + xk]     + sh_[kc + xk], 0.f);
            Xs[xr][xk + 1] = fmaxf(v.y * sc_[kc + xk + 1] + sh_[kc + xk + 1], 0.f);
        }
#pragma unroll
        for (int i = 0; i < 4; ++i) {
            int id2 = t + 256 * i;
            int wf = id2 >> 3, wk = (id2 & 7) * 4;
            *(float4*)&Ws[wf][wk] = *(const float4*)&W2[(size_t)wf * 256 + kc + wk];
        }
        __syncthreads();
#pragma unroll
        for (int k = 0; k < 32; ++k) {
            float w = Ws[f][k];
#pragma unroll
            for (int r = 0; r < 8; ++r) acc[r] += Xs[rh * 8 + r][k] * w;
        }
        __syncthreads();
    }
    float bv = b2[f], wv = W3[f];
    if (t < 16) rowsum[t] = 0.f;
    __syncthreads();
#pragma unroll
    for (int r = 0; r < 8; ++r) {
        float v = fmaxf(acc[r] + bv, 0.f) * wv;
#pragma unroll
        for (int off = 32; off; off >>= 1) v += __shfl_xor(v, off);
        if ((t & 63) == 0) atomicAdd(&rowsum[rh * 8 + r], v);
    }
    __syncthreads();
    if (t < 16) out[r0 + t] = rowsum[t] + b3[0];
}

// ================= launch =================

extern "C" void kernel_launch(void* const* d_in, const int* in_sizes, int n_in,
                              void* d_out, int out_size, void* d_ws, size_t ws_size,
                              hipStream_t stream) {
    const float* x        = (const float*)d_in[0];
    const int*   ei       = (const int*)d_in[1];
    const int*   batch    = (const int*)d_in[2];
    const float* esm      = (const float*)d_in[3];
    const float* tabf     = (const float*)d_in[4];
    const float* gat1_W   = (const float*)d_in[5];
    const float* gat1_as  = (const float*)d_in[6];
    const float* gat1_ad  = (const float*)d_in[7];
    const float* gat1_b   = (const float*)d_in[8];
    const float* gat2_W   = (const float*)d_in[9];
    const float* gat2_as  = (const float*)d_in[10];
    const float* gat2_ad  = (const float*)d_in[11];
    const float* gat2_b   = (const float*)d_in[12];
    const float* Wih_f    = (const float*)d_in[13];
    const float* bih_f    = (const float*)d_in[15];
    const float* bhh_f    = (const float*)d_in[16];
    const float* Wih_r    = (const float*)d_in[17];
    const float* bih_r    = (const float*)d_in[19];
    const float* bhh_r    = (const float*)d_in[20];
    const float* tab_W    = (const float*)d_in[21];
    const float* tab_b    = (const float*)d_in[22];
    const float* tab_g    = (const float*)d_in[23];
    const float* tab_bb   = (const float*)d_in[24];
    const float* fus1_W   = (const float*)d_in[25];
    const float* fus_g    = (const float*)d_in[27];
    const float* fus_bb   = (const float*)d_in[28];
    const float* fus2_W   = (const float*)d_in[29];
    const float* fus2_b   = (const float*)d_in[30];
    const float* fus3_W   = (const float*)d_in[31];
    const float* fus3_b   = (const float*)d_in[32];
    float* out = (float*)d_out;

    char* ws = (char*)d_ws;
    size_t off = 0;
    auto alloc = [&](size_t bytes) -> char* {
        char* p = ws + off;
        off += (bytes + 255) & ~(size_t)255;
        return p;
    };
    unsigned short* h0_bf = (unsigned short*)alloc((size_t)N_PAD * HD * 2);
    unsigned short* hA_bf = (unsigned short*)alloc((size_t)N_PAD * HD * 2);
    unsigned short* h2_bf = (unsigned short*)alloc((size_t)N_PAD * HD * 2);
    unsigned short* h_act = (unsigned short*)alloc((size_t)N_NODES * HD * 2);
    float* alpha_s = (float*)alloc((size_t)N_NODES * 4);
    float* alpha_d = (float*)alloc((size_t)N_NODES * 4);
    unsigned short* w2bf = (unsigned short*)alloc((size_t)HD * HD * 2);
    int*   row_beg = (int*)alloc((size_t)N_NODES * 4);
    int*   row_end = (int*)alloc((size_t)N_NODES * 4);
    int*   csr_src = (int*)alloc((size_t)NBUCK * CAP * 4);
    int*   pairs   = (int*)alloc((size_t)NBUCK * CAP * 4);
    int*   gstart  = (int*)alloc((size_t)(NB + 1) * 4);
    float* z1pre   = (float*)alloc((size_t)NB * 256 * 4);
    // zero-init group (contiguous, one memset): z, g_lstm, gcur, colsum, colsq
    float* z       = (float*)alloc((size_t)NB * 320 * 4);
    float* g_lstm  = (float*)alloc((size_t)NB * 512 * 4);
    int*   gcur    = (int*)alloc((size_t)NBUCK * 4);
    float* colsum  = (float*)alloc((size_t)256 * 4);
    float* colsq   = (float*)alloc((size_t)256 * 4);
    size_t zero_len = (size_t)((char*)colsq + 256 * 4 - (char*)z);
    hipMemsetAsync(z, 0, zero_len, stream);

    // 1) independent front: edge scatter+reserve | gat1 | LSTM GEMM | bounds | Wconv | tab
    megaA<<<SC_BLK + G1_BLK + LSTM_BLK + BND_BLK + WC_BLK + TAB_BLK, 256, 0, stream>>>(
        ei, gcur, pairs, x, gat1_W, gat1_as, gat1_ad, h0_bf, alpha_s, alpha_d,
        esm, Wih_f, Wih_r, g_lstm, batch, gstart, gat2_W, w2bf,
        tabf, tab_W, tab_b, tab_g, tab_bb, z);

    // 2) CSR finalize | LSTM nonlinearity
    megaB<<<NBUCK + 512, 256, 0, stream>>>(gcur, pairs, row_beg, row_end, csr_src,
                                           g_lstm, bih_f, bhh_f, bih_r, bhh_r, z);

    int aggGrid = (N_NODES + 3) / 4;

    // 3) GAT layer 1 aggregation
    gat_spmm<<<aggGrid, 256, 0, stream>>>(h0_bf, row_beg, row_end, csr_src,
                                          alpha_s, alpha_d, gat1_b, hA_bf);

    // 4) GAT2 linear (MFMA, alphas fused)
    gemm_mfma<<<N_PAD / 64, 256, 0, stream>>>(hA_bf, w2bf, gat2_as, gat2_ad,
                                              h2_bf, alpha_s, alpha_d, N_NODES);

    // 5) GAT layer 2 aggregation
    gat_spmm<<<aggGrid, 256, 0, stream>>>(h2_bf, row_beg, row_end, csr_src,
                                          alpha_s, alpha_d, gat2_b, h_act);

    // 6) mean pool -> z[:, 0:128)
    pool_kernel<<<(NB + 3) / 4, 256, 0, stream>>>(h_act, gstart, z);

    // 7) fus1 GEMM + BN column stats
    fus1_stats<<<dim3(64, 4), 256, 0, stream>>>(z, fus1_W, z1pre, colsum, colsq);

    // 8) BN+relu inline, fus2 GEMM, relu, final dot
    fus2_final<<<64, 256, 0, stream>>>(z1pre, colsum, colsq, fus_g, fus_bb,
                                       fus2_W, fus2_b, fus3_W, fus3_b, out);

    (void)in_sizes; (void)n_in; (void)out_size; (void)ws_size;
}